// Round 2
// baseline (660.860 us; speedup 1.0000x reference)
//
#include <hip/hip_runtime.h>
#include <hip/hip_bf16.h>

#define DIM   128      // feature/hidden width
#define KD    256      // 2*DIM (concat self||mean)
#define FAN   16       // neighbor fan-out
#define TILE  64       // nodes per block-tile
#define WSTRIDE 260    // bf16 elems per W column row (256 + 4 pad: 520 B, 8B-aligned, 2-way banks)
#define LDS_BYTES (128 * WSTRIDE * 2 + TILE * KD * 4)   // 66560 + 65536 = 132096

// out[n][col] = relu( sum_k x[n][k] * W[k][col] + b[col] ),
// x[n] = concat( hprev[self[n]], mean_j hprev[neigh[n][j]] )
__global__ __launch_bounds__(256, 1)
void sage_layer_kernel(const float* __restrict__ hprev,
                       const float* __restrict__ W,      // [256][128] row-major f32
                       const float* __restrict__ bias,   // [128]
                       const int*   __restrict__ nidx,   // [nnodes][16]
                       const int*   __restrict__ sidx,   // [nnodes]
                       float*       __restrict__ hout,   // [nnodes][128]
                       int nnodes, int ntiles)
{
    extern __shared__ unsigned char smem[];
    unsigned short* Wt = reinterpret_cast<unsigned short*>(smem);     // [128 cols][WSTRIDE] bf16
    float* xs = reinterpret_cast<float*>(smem + 128 * WSTRIDE * 2);   // [TILE][256] f32

    const int tid = threadIdx.x;

    // ---- pack W (f32 [k][col]) -> Wt (bf16 [col][k]) ----
    {
        const int col = tid & 127;
        const int kh  = (tid >> 7) * 128;    // 0 or 128
        for (int kk = 0; kk < 128; ++kk) {
            const int k = kh + kk;
            float f = W[(size_t)k * DIM + col];          // coalesced across threads
            __hip_bfloat16 h = __float2bfloat16(f);      // RNE
            Wt[col * WSTRIDE + k] = *reinterpret_cast<unsigned short*>(&h);
        }
    }

    // compute-phase mapping: 4 cols (stride 32) x 8 nodes per thread
    const int cb = tid & 31;       // cols cb, cb+32, cb+64, cb+96
    const int ng = tid >> 5;       // node group 0..7 -> nodes ng*8 .. ng*8+7
    const float b0 = bias[cb], b1 = bias[cb + 32], b2 = bias[cb + 64], b3 = bias[cb + 96];

    const unsigned short* w0p = Wt + (size_t)cb * WSTRIDE;
    const unsigned short* w1p = w0p + 32 * WSTRIDE;
    const unsigned short* w2p = w1p + 32 * WSTRIDE;
    const unsigned short* w3p = w2p + 32 * WSTRIDE;

    for (int tile = blockIdx.x; tile < ntiles; tile += gridDim.x) {
        const int nb = tile * TILE;
        __syncthreads();   // W visible (1st iter); xs free of prev tile's readers

        // ---- gather: build xs[64][256] = [self || mean(neigh)] ----
        {
            const int c4 = (tid & 31) * 4;        // 4 cols per lane
            #pragma unroll 2
            for (int pass = 0; pass < 8; ++pass) {
                const int ln = pass * 8 + (tid >> 5);   // local node 0..63
                int n = nb + ln;
                if (n >= nnodes) n = nnodes - 1;        // tail: duplicate, stores guarded
                const float4 sv = *reinterpret_cast<const float4*>(
                    hprev + (size_t)sidx[n] * DIM + c4);
                const int* nn = nidx + (size_t)n * FAN;
                float sx = 0.f, sy = 0.f, sz = 0.f, sw = 0.f;
                #pragma unroll
                for (int j = 0; j < FAN; ++j) {
                    const float4 v = *reinterpret_cast<const float4*>(
                        hprev + (size_t)nn[j] * DIM + c4);
                    sx += v.x; sy += v.y; sz += v.z; sw += v.w;
                }
                float4 mv;
                mv.x = sx * 0.0625f; mv.y = sy * 0.0625f;
                mv.z = sz * 0.0625f; mv.w = sw * 0.0625f;
                *reinterpret_cast<float4*>(xs + ln * KD + c4) = sv;
                *reinterpret_cast<float4*>(xs + ln * KD + DIM + c4) = mv;
            }
        }
        __syncthreads();

        // ---- compute: 8 nodes x 4 cols per thread ----
        float acc[8][4];
        #pragma unroll
        for (int m = 0; m < 8; ++m)
            #pragma unroll
            for (int c = 0; c < 4; ++c) acc[m][c] = 0.f;

        const float* xp = xs + ng * 8 * KD;

        #pragma unroll 2
        for (int k = 0; k < KD; k += 4) {
            const uint2 u0 = *reinterpret_cast<const uint2*>(w0p + k);
            const uint2 u1 = *reinterpret_cast<const uint2*>(w1p + k);
            const uint2 u2 = *reinterpret_cast<const uint2*>(w2p + k);
            const uint2 u3 = *reinterpret_cast<const uint2*>(w3p + k);
            float wv[4][4];
            wv[0][0] = __uint_as_float(u0.x << 16);
            wv[0][1] = __uint_as_float(u0.x & 0xffff0000u);
            wv[0][2] = __uint_as_float(u0.y << 16);
            wv[0][3] = __uint_as_float(u0.y & 0xffff0000u);
            wv[1][0] = __uint_as_float(u1.x << 16);
            wv[1][1] = __uint_as_float(u1.x & 0xffff0000u);
            wv[1][2] = __uint_as_float(u1.y << 16);
            wv[1][3] = __uint_as_float(u1.y & 0xffff0000u);
            wv[2][0] = __uint_as_float(u2.x << 16);
            wv[2][1] = __uint_as_float(u2.x & 0xffff0000u);
            wv[2][2] = __uint_as_float(u2.y << 16);
            wv[2][3] = __uint_as_float(u2.y & 0xffff0000u);
            wv[3][0] = __uint_as_float(u3.x << 16);
            wv[3][1] = __uint_as_float(u3.x & 0xffff0000u);
            wv[3][2] = __uint_as_float(u3.y << 16);
            wv[3][3] = __uint_as_float(u3.y & 0xffff0000u);
            #pragma unroll
            for (int m = 0; m < 8; ++m) {
                const float4 xv = *reinterpret_cast<const float4*>(xp + m * KD + k);
                #pragma unroll
                for (int c = 0; c < 4; ++c) {
                    acc[m][c] = fmaf(xv.x, wv[c][0], acc[m][c]);
                    acc[m][c] = fmaf(xv.y, wv[c][1], acc[m][c]);
                    acc[m][c] = fmaf(xv.z, wv[c][2], acc[m][c]);
                    acc[m][c] = fmaf(xv.w, wv[c][3], acc[m][c]);
                }
            }
        }

        // ---- epilogue: bias + relu, coalesced stores ----
        #pragma unroll
        for (int m = 0; m < 8; ++m) {
            const int n = nb + ng * 8 + m;
            if (n < nnodes) {
                float* orow = hout + (size_t)n * DIM;
                float v0 = acc[m][0] + b0; orow[cb]      = v0 > 0.f ? v0 : 0.f;
                float v1 = acc[m][1] + b1; orow[cb + 32] = v1 > 0.f ? v1 : 0.f;
                float v2 = acc[m][2] + b2; orow[cb + 64] = v2 > 0.f ? v2 : 0.f;
                float v3 = acc[m][3] + b3; orow[cb + 96] = v3 > 0.f ? v3 : 0.f;
            }
        }
    }
}

extern "C" void kernel_launch(void* const* d_in, const int* in_sizes, int n_in,
                              void* d_out, int out_size, void* d_ws, size_t ws_size,
                              hipStream_t stream)
{
    const float* features = (const float*)d_in[0];
    const float* W1       = (const float*)d_in[1];
    const float* b1       = (const float*)d_in[2];
    const float* W2       = (const float*)d_in[3];
    const float* b2       = (const float*)d_in[4];
    const int*   n1idx    = (const int*)d_in[5];
    const int*   s1idx    = (const int*)d_in[6];
    const int*   n2idx    = (const int*)d_in[7];
    const int*   s2idx    = (const int*)d_in[8];

    const int N1 = in_sizes[6];   // 100000
    const int N2 = in_sizes[8];   // 50000

    float* h1  = (float*)d_ws;            // [N1][128] f32 = 51.2 MB
    float* out = (float*)d_out;

    (void)hipFuncSetAttribute(reinterpret_cast<const void*>(sage_layer_kernel),
                              hipFuncAttributeMaxDynamicSharedMemorySize, LDS_BYTES);

    const int t1 = (N1 + TILE - 1) / TILE;   // 1563
    const int t2 = (N2 + TILE - 1) / TILE;   // 782

    sage_layer_kernel<<<t1, 256, LDS_BYTES, stream>>>(features, W1, b1, n1idx, s1idx, h1, N1, t1);
    sage_layer_kernel<<<t2, 256, LDS_BYTES, stream>>>(h1,       W2, b2, n2idx, s2idx, out, N2, t2);
}

// Round 4
// 408.949 us; speedup vs baseline: 1.6160x; 1.6160x over previous
//
#include <hip/hip_runtime.h>
#include <hip/hip_bf16.h>

typedef __attribute__((ext_vector_type(8))) short bf16x8;
typedef __attribute__((ext_vector_type(4))) float f32x4;

#define DIM   128     // feature/hidden width
#define KD    256     // 2*DIM
#define FAN   16
#define TILE  32      // nodes per block-tile
#define XS_STRIDE 264 // bf16 elems per xs row: 528 B = 33*16 (16B-aligned rows, banks spread)

// x[n] = concat(hprev[self[n]], mean_j hprev[neigh[n][j]]) -> bf16 in LDS
// out[n][c] = relu(sum_k x[n][k] * W[k][c] + b[c]) via mfma_f32_16x16x32_bf16
__global__ __launch_bounds__(256, 4)
void sage_fused(const float* __restrict__ hprev,
                const float* __restrict__ W,      // [256][128] row-major f32
                const float* __restrict__ bias,   // [128]
                const int*   __restrict__ nidx,   // [nnodes][16]
                const int*   __restrict__ sidx,   // [nnodes]
                float*       __restrict__ hout,   // [nnodes][128]
                int nnodes, int ntiles)
{
    __shared__ unsigned short xs[TILE * XS_STRIDE];   // 16896 B

    const int tid  = threadIdx.x;
    const int lane = tid & 63;
    const int wid  = tid >> 6;      // wave 0..3
    const int l15  = lane & 15;
    const int lg   = lane >> 4;     // 0..3

    // ---- preload W fragments (per wave: 2 n-tiles x 8 k-steps), bf16 in regs ----
    // B-frag layout (16x16x32): col = lane&15, k = (lane>>4)*8 + j
    bf16x8 wf[2][8];
    #pragma unroll
    for (int t = 0; t < 2; ++t) {
        const int col = (2 * wid + t) * 16 + l15;
        #pragma unroll
        for (int ks = 0; ks < 8; ++ks) {
            const int kb = ks * 32 + lg * 8;
            bf16x8 v;
            #pragma unroll
            for (int j = 0; j < 8; ++j) {
                __hip_bfloat16 h = __float2bfloat16(W[(size_t)(kb + j) * DIM + col]);
                v[j] = *reinterpret_cast<const short*>(&h);
            }
            wf[t][ks] = v;
        }
    }
    float bv[2];
    bv[0] = bias[(2 * wid + 0) * 16 + l15];
    bv[1] = bias[(2 * wid + 1) * 16 + l15];

    for (int tile = blockIdx.x; tile < ntiles; tile += gridDim.x) {
        const int nb = tile * TILE;
        __syncthreads();   // xs free of previous tile's readers

        // ---- gather: one wave per node, lane owns col pair (2*lane, 2*lane+1) ----
        #pragma unroll 2
        for (int i = 0; i < 8; ++i) {
            int n = nb + wid * 8 + i;
            if (n >= nnodes) n = nnodes - 1;            // tail dup; stores guarded
            const float2 sv = *reinterpret_cast<const float2*>(
                hprev + (size_t)sidx[n] * DIM + 2 * lane);
            const int* nn = nidx + (size_t)n * FAN;
            float ax = 0.f, ay = 0.f;
            #pragma unroll
            for (int j = 0; j < FAN; ++j) {
                const float2 v = *reinterpret_cast<const float2*>(
                    hprev + (size_t)nn[j] * DIM + 2 * lane);
                ax += v.x; ay += v.y;
            }
            ax *= 0.0625f; ay *= 0.0625f;

            __hip_bfloat16 hsx = __float2bfloat16(sv.x);
            __hip_bfloat16 hsy = __float2bfloat16(sv.y);
            __hip_bfloat16 hmx = __float2bfloat16(ax);
            __hip_bfloat16 hmy = __float2bfloat16(ay);
            unsigned int su = (unsigned int)(*(unsigned short*)&hsx)
                            | ((unsigned int)(*(unsigned short*)&hsy) << 16);
            unsigned int mu = (unsigned int)(*(unsigned short*)&hmx)
                            | ((unsigned int)(*(unsigned short*)&hmy) << 16);
            const int ln = wid * 8 + i;
            unsigned int* row = reinterpret_cast<unsigned int*>(xs + (size_t)ln * XS_STRIDE);
            row[lane]      = su;   // self half: k = 2*lane .. +1
            row[64 + lane] = mu;   // mean half: k = 128 + 2*lane .. +1
        }
        __syncthreads();

        // ---- MFMA: per wave 2 m-subtiles x 2 n-tiles, K=256 in 8 steps ----
        f32x4 acc[2][2];
        #pragma unroll
        for (int mt = 0; mt < 2; ++mt)
            #pragma unroll
            for (int t = 0; t < 2; ++t)
                acc[mt][t] = (f32x4){0.f, 0.f, 0.f, 0.f};

        #pragma unroll
        for (int ks = 0; ks < 8; ++ks) {
            bf16x8 af[2];
            #pragma unroll
            for (int mt = 0; mt < 2; ++mt) {
                const unsigned short* p =
                    xs + (size_t)(mt * 16 + l15) * XS_STRIDE + ks * 32 + lg * 8;
                af[mt] = *reinterpret_cast<const bf16x8*>(p);
            }
            #pragma unroll
            for (int mt = 0; mt < 2; ++mt)
                #pragma unroll
                for (int t = 0; t < 2; ++t)
                    acc[mt][t] = __builtin_amdgcn_mfma_f32_16x16x32_bf16(
                        af[mt], wf[t][ks], acc[mt][t], 0, 0, 0);
        }

        // ---- epilogue: bias + relu; C/D: col = lane&15, row = (lane>>4)*4 + r ----
        #pragma unroll
        for (int mt = 0; mt < 2; ++mt) {
            #pragma unroll
            for (int t = 0; t < 2; ++t) {
                const int col = (2 * wid + t) * 16 + l15;
                #pragma unroll
                for (int r = 0; r < 4; ++r) {
                    const int n = nb + mt * 16 + lg * 4 + r;
                    if (n < nnodes) {
                        float v = acc[mt][t][r] + bv[t];
                        hout[(size_t)n * DIM + col] = v > 0.f ? v : 0.f;
                    }
                }
            }
        }
    }
}

extern "C" void kernel_launch(void* const* d_in, const int* in_sizes, int n_in,
                              void* d_out, int out_size, void* d_ws, size_t ws_size,
                              hipStream_t stream)
{
    const float* features = (const float*)d_in[0];
    const float* W1       = (const float*)d_in[1];
    const float* b1       = (const float*)d_in[2];
    const float* W2       = (const float*)d_in[3];
    const float* b2       = (const float*)d_in[4];
    const int*   n1idx    = (const int*)d_in[5];
    const int*   s1idx    = (const int*)d_in[6];
    const int*   n2idx    = (const int*)d_in[7];
    const int*   s2idx    = (const int*)d_in[8];

    const int N1 = in_sizes[6];   // 100000
    const int N2 = in_sizes[8];   // 50000

    float* h1  = (float*)d_ws;    // [N1][128] f32 = 51.2 MB
    float* out = (float*)d_out;

    const int t1 = (N1 + TILE - 1) / TILE;   // 3125
    const int t2 = (N2 + TILE - 1) / TILE;   // 1563

    sage_fused<<<t1, 256, 0, stream>>>(features, W1, b1, n1idx, s1idx, h1, N1, t1);
    sage_fused<<<t2, 256, 0, stream>>>(h1,       W2, b2, n2idx, s2idx, out, N2, t2);
}

// Round 5
// 274.246 us; speedup vs baseline: 2.4097x; 1.4912x over previous
//
#include <hip/hip_runtime.h>
#include <hip/hip_bf16.h>

typedef __attribute__((ext_vector_type(8))) short bf16x8;
typedef __attribute__((ext_vector_type(4))) float f32x4;

#define DIM   128
#define KD    256
#define FAN   16
#define TILE  32
#define XS_STRIDE 264            // shorts per xs row (528 B, 16B-aligned, banks spread)
#define WP_LAYER_SHORTS (8*8*64*8)   // 32768 shorts = 64 KiB per layer

__device__ __forceinline__ unsigned short f2bf(float f) {
    __hip_bfloat16 h = __float2bfloat16(f);           // RNE
    return *reinterpret_cast<unsigned short*>(&h);
}
__device__ __forceinline__ float bflo(unsigned int u) { return __uint_as_float(u << 16); }
__device__ __forceinline__ float bfhi(unsigned int u) { return __uint_as_float(u & 0xffff0000u); }

// ---- prep: f32 -> packed bf16 (4 elems per uint2) ----
__global__ __launch_bounds__(256)
void cvt_bf16_kernel(const float* __restrict__ in, uint2* __restrict__ out, int n4)
{
    const int stride = gridDim.x * blockDim.x;
    for (int i = blockIdx.x * blockDim.x + threadIdx.x; i < n4; i += stride) {
        const float4 v = reinterpret_cast<const float4*>(in)[i];
        uint2 o;
        o.x = (unsigned int)f2bf(v.x) | ((unsigned int)f2bf(v.y) << 16);
        o.y = (unsigned int)f2bf(v.z) | ((unsigned int)f2bf(v.w) << 16);
        out[i] = o;
    }
}

// ---- pack W (f32 [k][col]) into MFMA B-frag order: wp[t][ks][lane][j] bf16 ----
// frag semantics: lane=(lg<<4)|l15 holds B[k=ks*32+lg*8+j][col=t*16+l15]
__global__ __launch_bounds__(256)
void wpack_kernel(const float* __restrict__ W1, const float* __restrict__ W2,
                  unsigned short* __restrict__ wp)
{
    const int b = blockIdx.x;                  // 0..15: [layer][t]
    const float* W = (b & 8) ? W2 : W1;
    unsigned short* dst = wp + ((b & 8) ? WP_LAYER_SHORTS : 0);
    const int t   = b & 7;
    const int tid = threadIdx.x;
    const int lane = tid & 63, wid = tid >> 6;
    const int l15 = lane & 15, lg = lane >> 4;
    #pragma unroll
    for (int s = 0; s < 2; ++s) {
        const int ks = wid + s * 4;
        bf16x8 v;
        #pragma unroll
        for (int j = 0; j < 8; ++j)
            v[j] = (short)f2bf(W[(size_t)(ks * 32 + lg * 8 + j) * DIM + t * 16 + l15]);
        *reinterpret_cast<bf16x8*>(dst + ((size_t)(t * 8 + ks) * 64 + lane) * 8) = v;
    }
}

// ---- fused SAGE layer: gather+mean -> bf16 LDS -> MFMA -> bias+relu ----
template<bool SRC_BF, bool DST_BF>
__global__ __launch_bounds__(256, 4)
void sage_layer(const void* __restrict__ src,                 // [n0][128] bf16 or f32
                const unsigned short* __restrict__ wp,        // frag-packed bf16
                const float* __restrict__ bias,
                const int*  __restrict__ nidx,
                const int*  __restrict__ sidx,
                void* __restrict__ dst,                       // [n][128] bf16 or f32
                int nnodes)
{
    __shared__ unsigned short xs[TILE * XS_STRIDE];           // 16896 B

    const int tid  = threadIdx.x;
    const int lane = tid & 63;
    const int wid  = tid >> 6;
    const int l15  = lane & 15;
    const int lg   = lane >> 4;
    const int nb   = blockIdx.x * TILE;

    // ---- gather: one wave per node, lane owns channel pair (2*lane, 2*lane+1) ----
    #pragma unroll 4
    for (int i = 0; i < 8; ++i) {
        int n = nb + wid * 8 + i;
        if (n >= nnodes) n = nnodes - 1;                      // tail dup; stores guarded
        const int sn = sidx[n];
        const int* nn = nidx + (size_t)n * FAN;
        unsigned int su;
        float ax = 0.f, ay = 0.f;
        if (SRC_BF) {
            const unsigned int* srcu = (const unsigned int*)src;
            su = srcu[(size_t)sn * 64 + lane];
            #pragma unroll
            for (int j = 0; j < FAN; ++j) {
                const unsigned int u = srcu[(size_t)nn[j] * 64 + lane];
                ax += bflo(u); ay += bfhi(u);
            }
        } else {
            const float* srcf = (const float*)src;
            const float2 sv = *reinterpret_cast<const float2*>(srcf + (size_t)sn * DIM + 2 * lane);
            su = (unsigned int)f2bf(sv.x) | ((unsigned int)f2bf(sv.y) << 16);
            #pragma unroll
            for (int j = 0; j < FAN; ++j) {
                const float2 v = *reinterpret_cast<const float2*>(srcf + (size_t)nn[j] * DIM + 2 * lane);
                ax += v.x; ay += v.y;
            }
        }
        ax *= 0.0625f; ay *= 0.0625f;
        const unsigned int mu = (unsigned int)f2bf(ax) | ((unsigned int)f2bf(ay) << 16);
        unsigned int* row = reinterpret_cast<unsigned int*>(xs + (size_t)(wid * 8 + i) * XS_STRIDE);
        row[lane]      = su;   // self half:  k = 2*lane, 2*lane+1
        row[64 + lane] = mu;   // mean half:  k = 128 + 2*lane, +1
    }

    // ---- W fragments: 16 coalesced b128 loads per lane ----
    bf16x8 wf[2][8];
    #pragma unroll
    for (int t = 0; t < 2; ++t) {
        const int tg = 2 * wid + t;
        #pragma unroll
        for (int ks = 0; ks < 8; ++ks)
            wf[t][ks] = *reinterpret_cast<const bf16x8*>(
                wp + ((size_t)(tg * 8 + ks) * 64 + lane) * 8);
    }
    float bv[2];
    bv[0] = bias[(2 * wid + 0) * 16 + l15];
    bv[1] = bias[(2 * wid + 1) * 16 + l15];

    __syncthreads();

    // ---- MFMA: per wave 2 m-subtiles x 2 n-tiles, K=256 in 8 steps ----
    f32x4 acc[2][2];
    #pragma unroll
    for (int mt = 0; mt < 2; ++mt)
        #pragma unroll
        for (int t = 0; t < 2; ++t)
            acc[mt][t] = (f32x4){0.f, 0.f, 0.f, 0.f};

    #pragma unroll
    for (int ks = 0; ks < 8; ++ks) {
        bf16x8 af[2];
        #pragma unroll
        for (int mt = 0; mt < 2; ++mt)
            af[mt] = *reinterpret_cast<const bf16x8*>(
                xs + (size_t)(mt * 16 + l15) * XS_STRIDE + ks * 32 + lg * 8);
        #pragma unroll
        for (int mt = 0; mt < 2; ++mt)
            #pragma unroll
            for (int t = 0; t < 2; ++t)
                acc[mt][t] = __builtin_amdgcn_mfma_f32_16x16x32_bf16(
                    af[mt], wf[t][ks], acc[mt][t], 0, 0, 0);
    }

    // ---- epilogue: bias + relu; C/D: col = lane&15, row = (lane>>4)*4 + r ----
    #pragma unroll
    for (int mt = 0; mt < 2; ++mt) {
        #pragma unroll
        for (int t = 0; t < 2; ++t) {
            const int col = (2 * wid + t) * 16 + l15;
            #pragma unroll
            for (int r = 0; r < 4; ++r) {
                const int n = nb + mt * 16 + lg * 4 + r;
                if (n < nnodes) {
                    const float v = acc[mt][t][r] + bv[t];
                    const float rv = v > 0.f ? v : 0.f;
                    if (DST_BF)
                        ((unsigned short*)dst)[(size_t)n * DIM + col] = f2bf(rv);
                    else
                        ((float*)dst)[(size_t)n * DIM + col] = rv;
                }
            }
        }
    }
}

extern "C" void kernel_launch(void* const* d_in, const int* in_sizes, int n_in,
                              void* d_out, int out_size, void* d_ws, size_t ws_size,
                              hipStream_t stream)
{
    const float* features = (const float*)d_in[0];
    const float* W1       = (const float*)d_in[1];
    const float* b1       = (const float*)d_in[2];
    const float* W2       = (const float*)d_in[3];
    const float* b2       = (const float*)d_in[4];
    const int*   n1idx    = (const int*)d_in[5];
    const int*   s1idx    = (const int*)d_in[6];
    const int*   n2idx    = (const int*)d_in[7];
    const int*   s2idx    = (const int*)d_in[8];

    const int NF = in_sizes[0];        // 200000*128
    const int N1 = in_sizes[6];        // 100000
    const int N2 = in_sizes[8];        // 50000

    const size_t fbf_bytes = (size_t)NF * 2;                  // 51.2 MB
    const size_t h1_bytes  = (size_t)N1 * DIM * 2;            // 25.6 MB
    const size_t wp_bytes  = (size_t)2 * WP_LAYER_SHORTS * 2; // 128 KiB
    const bool full = ws_size >= fbf_bytes + h1_bytes + wp_bytes;

    unsigned char* ws = (unsigned char*)d_ws;
    unsigned short* fbf = nullptr;
    unsigned short* h1  = nullptr;
    unsigned short* wpk = nullptr;
    if (full) {
        fbf = (unsigned short*)ws;
        h1  = (unsigned short*)(ws + fbf_bytes);
        wpk = (unsigned short*)(ws + fbf_bytes + h1_bytes);
    } else {
        h1  = (unsigned short*)ws;
        wpk = (unsigned short*)(ws + h1_bytes);
    }

    wpack_kernel<<<16, 256, 0, stream>>>(W1, W2, wpk);
    if (full)
        cvt_bf16_kernel<<<2048, 256, 0, stream>>>(features, (uint2*)fbf, NF / 4);

    const int t1 = (N1 + TILE - 1) / TILE;   // 3125
    const int t2 = (N2 + TILE - 1) / TILE;   // 1563

    if (full)
        sage_layer<true,  true><<<t1, 256, 0, stream>>>(fbf, wpk, b1, n1idx, s1idx, h1, N1);
    else
        sage_layer<false, true><<<t1, 256, 0, stream>>>(features, wpk, b1, n1idx, s1idx, h1, N1);

    sage_layer<true, false><<<t2, 256, 0, stream>>>(h1, wpk + WP_LAYER_SHORTS, b2,
                                                    n2idx, s2idx, (float*)d_out, N2);
}